// Round 3
// baseline (563.684 us; speedup 1.0000x reference)
//
#include <hip/hip_runtime.h>
#include <hip/hip_bf16.h>
#include <stdint.h>
#include <stddef.h>

// MoE: T=4096 tokens, D=1024, H=4096, E=8, top-2. fp32 in/out, bf16 MFMA inside.
// Grouped GEMM: 256x128 tile, BK=64, 8 waves, 3-deep gload_lds pipeline with
// counted vmcnt(6) (T3+T4) + setprio (T5) + both-sides XOR swizzle (T2).

#define T_TOK 4096
#define DIM   1024
#define HID   4096
#define NE    8

typedef unsigned short u16;
typedef __bf16 bf16x8 __attribute__((ext_vector_type(8)));
typedef float  f32x4  __attribute__((ext_vector_type(4)));
typedef u16    u16x8  __attribute__((ext_vector_type(8)));

__device__ __forceinline__ u16 f2bf(float f) {
  union { float f; uint32_t u; } v; v.f = f;
  uint32_t u = v.u;
  return (u16)((u + 0x7fffu + ((u >> 16) & 1u)) >> 16);   // RNE
}

__device__ __forceinline__ void async_load16(const void* g, void* l) {
  typedef __attribute__((address_space(1))) void GPtr;
  typedef __attribute__((address_space(3))) void LPtr;
  __builtin_amdgcn_global_load_lds((GPtr*)g, (LPtr*)l, 16, 0, 0);
}

// ---------------- Router ----------------------------------------------------
__global__ void router_kernel(const float* __restrict__ x, const float* __restrict__ Wr,
                              const float* __restrict__ br, const float* __restrict__ gb,
                              int* __restrict__ counts, int* __restrict__ lists,
                              float* __restrict__ gate_p) {
  const int t = blockIdx.x * 4 + (threadIdx.x >> 6);
  const int lane = threadIdx.x & 63;
  const float* xr = x + (size_t)t * DIM;
  float acc[NE];
#pragma unroll
  for (int e = 0; e < NE; ++e) acc[e] = 0.f;
#pragma unroll
  for (int i = 0; i < DIM / 64; ++i) {
    const int k = i * 64 + lane;
    const float xv = xr[k];
    const float4 w0 = *reinterpret_cast<const float4*>(Wr + (size_t)k * NE);
    const float4 w1 = *reinterpret_cast<const float4*>(Wr + (size_t)k * NE + 4);
    acc[0] += xv * w0.x; acc[1] += xv * w0.y; acc[2] += xv * w0.z; acc[3] += xv * w0.w;
    acc[4] += xv * w1.x; acc[5] += xv * w1.y; acc[6] += xv * w1.z; acc[7] += xv * w1.w;
  }
#pragma unroll
  for (int off = 32; off >= 1; off >>= 1) {
#pragma unroll
    for (int e = 0; e < NE; ++e) acc[e] += __shfl_xor(acc[e], off);
  }
  if (lane == 0) {
    float lg[NE];
#pragma unroll
    for (int e = 0; e < NE; ++e) lg[e] = acc[e] + br[e] + gb[e];
    int i0 = 0;
#pragma unroll
    for (int e = 1; e < NE; ++e) if (lg[e] > lg[i0]) i0 = e;
    int i1 = (i0 == 0) ? 1 : 0;
#pragma unroll
    for (int e = 0; e < NE; ++e) if (e != i0 && lg[e] > lg[i1]) i1 = e;
    const float ev = expf(lg[i1] - lg[i0]);         // <= 1
    const float p0 = 1.f / (1.f + ev);
    const float p1 = ev / (1.f + ev);
    const int pos0 = atomicAdd(&counts[i0], 1);
    lists[i0 * T_TOK + pos0] = t * 2 + 0;
    const int pos1 = atomicAdd(&counts[i1], 1);
    lists[i1 * T_TOK + pos1] = t * 2 + 1;
    gate_p[t * 2 + 0] = p0;
    gate_p[t * 2 + 1] = p1;
  }
}

// ---------------- fp32 -> bf16 (x) ------------------------------------------
__global__ void cvt_x_kernel(const float* __restrict__ in, u16* __restrict__ out, int n8) {
  const int i = blockIdx.x * blockDim.x + threadIdx.x;
  if (i >= n8) return;
  const float4 a = reinterpret_cast<const float4*>(in)[2 * i];
  const float4 b = reinterpret_cast<const float4*>(in)[2 * i + 1];
  u16x8 r;
  r[0] = f2bf(a.x); r[1] = f2bf(a.y); r[2] = f2bf(a.z); r[3] = f2bf(a.w);
  r[4] = f2bf(b.x); r[5] = f2bf(b.y); r[6] = f2bf(b.z); r[7] = f2bf(b.w);
  *reinterpret_cast<u16x8*>(out + (size_t)i * 8) = r;
}

// ---------------- fp32 [E][K][N] -> bf16 [E][N][K] --------------------------
__global__ void cvt_w_kernel(const float* __restrict__ in, u16* __restrict__ out,
                             int K, int N) {
  __shared__ float tile[64][65];
  const int e = blockIdx.z;
  const int n0 = blockIdx.x * 64, k0 = blockIdx.y * 64;
  const int tid = threadIdx.x;
  const float* src = in + (size_t)e * K * N;
#pragma unroll
  for (int r = 0; r < 16; ++r) {
    const int kr = r * 4 + (tid >> 6);
    tile[kr][tid & 63] = src[(size_t)(k0 + kr) * N + n0 + (tid & 63)];
  }
  __syncthreads();
  u16* dst = out + (size_t)e * N * K;
#pragma unroll
  for (int r = 0; r < 8; ++r) {
    const int nr = r * 8 + (tid >> 5);
    const int kc = (tid & 31) * 2;
    ushort2 v;
    v.x = f2bf(tile[kc][nr]);
    v.y = f2bf(tile[kc + 1][nr]);
    *reinterpret_cast<ushort2*>(&dst[(size_t)(n0 + nr) * K + k0 + kc]) = v;
  }
}

// ---------------- Grouped GEMM, 3-buffer counted-vmcnt pipeline --------------
// LDS (u16 units): A: buf b at b*16384, row r at r*64, slot s (16B) at s*8.
//                  B: 49152 + b*8192 + r*64 + s*8.
// Swizzle: stored slot = logical ^ (row&7), both on the gload source and reads.
template <int KT, int NT, int PHASE>
__global__ __launch_bounds__(512, 2)
void gemm_kernel(const u16* __restrict__ Abase, const u16* __restrict__ Bt,
                 const float* __restrict__ bias, const int* __restrict__ counts,
                 const int* __restrict__ lists, const float* __restrict__ gate_p,
                 u16* __restrict__ hout, float* __restrict__ yout) {
  const int e = blockIdx.z;
  const int cnt = counts[e];
  const int m0 = blockIdx.y * 256;
  if (m0 >= cnt) return;
  const int n0 = blockIdx.x * 128;
  const int tid = threadIdx.x;
  const int lane = tid & 63, w = tid >> 6;
  const int wm = w >> 2, wn = w & 3;           // wave tile: rows wm*128, cols wn*32

  __shared__ alignas(16) u16 lds[73728];       // 144 KB: A 3x32K + B 3x16K
  __shared__ int rowp[256];

  if (tid < 256) {
    const int idx = m0 + tid;
    rowp[tid] = lists[e * T_TOK + (idx < cnt ? idx : cnt - 1)];
  }
  __syncthreads();

  // Per-thread staged rows: A instr i covers row i*64 + w*8 + (lane>>3).
  const int srow = w * 8 + (lane >> 3);
  const int sslot = (lane & 7) ^ (lane >> 3);          // pre-swizzled k-slot
  const u16* aP[4];
#pragma unroll
  for (int i = 0; i < 4; ++i) {
    const int p = rowp[i * 64 + srow];
    const int arow = (PHASE == 1) ? (p >> 1) : p;
    aP[i] = Abase + (size_t)arow * KT + sslot * 8;
  }
  const u16* bP[2];
#pragma unroll
  for (int i = 0; i < 2; ++i)
    bP[i] = Bt + ((size_t)e * NT + n0 + i * 64 + srow) * KT + sslot * 8;

  constexpr int nkt = KT / 64;

#define STAGE(TT, BB)                                                          \
  {                                                                            \
    _Pragma("unroll")                                                          \
    for (int i = 0; i < 4; ++i)                                                \
      async_load16(aP[i] + (TT) * 64, &lds[(BB) * 16384 + (i * 64 + w * 8) * 64]); \
    _Pragma("unroll")                                                          \
    for (int i = 0; i < 2; ++i)                                                \
      async_load16(bP[i] + (TT) * 64,                                          \
                   &lds[49152 + (BB) * 8192 + (i * 64 + w * 8) * 64]);         \
  }

  f32x4 acc[8][2];
#pragma unroll
  for (int a = 0; a < 8; ++a)
#pragma unroll
    for (int b = 0; b < 2; ++b) acc[a][b] = f32x4{0.f, 0.f, 0.f, 0.f};

  // ---- prologue: tiles 0,1 into bufs 0,1; wait tile0 landed ----
  STAGE(0, 0);
  STAGE(1, 1);
  asm volatile("s_waitcnt vmcnt(6)" ::: "memory");
  __builtin_amdgcn_sched_barrier(0);
  __builtin_amdgcn_s_barrier();

  int cur = 0;
  const int l15 = lane & 15, lks = lane >> 4;
  for (int t = 0; t < nkt; ++t) {
    const int abase = cur * 16384;
    const int bbase = 49152 + cur * 8192;
    bf16x8 bf[2][2];
    // ---- P0: A-half0 frags + B frags; stage t+2; MFMA mh=0 ----
    {
      bf16x8 af[4][2];
#pragma unroll
      for (int fm = 0; fm < 4; ++fm) {
        const int r = wm * 128 + fm * 16 + l15;
#pragma unroll
        for (int ks = 0; ks < 2; ++ks) {
          const int ls = ks * 4 + lks;
          af[fm][ks] = *reinterpret_cast<const bf16x8*>(
              &lds[abase + r * 64 + ((ls ^ (r & 7)) * 8)]);
        }
      }
#pragma unroll
      for (int nf = 0; nf < 2; ++nf) {
        const int r = wn * 32 + nf * 16 + l15;
#pragma unroll
        for (int ks = 0; ks < 2; ++ks) {
          const int ls = ks * 4 + lks;
          bf[nf][ks] = *reinterpret_cast<const bf16x8*>(
              &lds[bbase + r * 64 + ((ls ^ (r & 7)) * 8)]);
        }
      }
      if (t + 2 < nkt) {
        const int nxt2 = (cur == 0) ? 2 : cur - 1;   // (t+2)%3
        STAGE(t + 2, nxt2);
      }
      __builtin_amdgcn_s_barrier();
      __builtin_amdgcn_s_setprio(1);
#pragma unroll
      for (int fm = 0; fm < 4; ++fm)
#pragma unroll
        for (int nf = 0; nf < 2; ++nf)
#pragma unroll
          for (int ks = 0; ks < 2; ++ks)
            acc[fm][nf] = __builtin_amdgcn_mfma_f32_16x16x32_bf16(
                af[fm][ks], bf[nf][ks], acc[fm][nf], 0, 0, 0);
      __builtin_amdgcn_s_setprio(0);
      __builtin_amdgcn_s_barrier();
    }
    // ---- P1: A-half1 frags; tile-end vmcnt; MFMA mh=1 ----
    {
      bf16x8 af[4][2];
#pragma unroll
      for (int fm = 0; fm < 4; ++fm) {
        const int r = wm * 128 + 64 + fm * 16 + l15;
#pragma unroll
        for (int ks = 0; ks < 2; ++ks) {
          const int ls = ks * 4 + lks;
          af[fm][ks] = *reinterpret_cast<const bf16x8*>(
              &lds[abase + r * 64 + ((ls ^ (r & 7)) * 8)]);
        }
      }
      if (t < nkt - 2) {
        asm volatile("s_waitcnt vmcnt(6)" ::: "memory");   // t+1 landed; t+2 in flight
      } else if (t == nkt - 2) {
        asm volatile("s_waitcnt vmcnt(0)" ::: "memory");   // tail: force t+1
      }
      __builtin_amdgcn_sched_barrier(0);
      __builtin_amdgcn_s_barrier();
      __builtin_amdgcn_s_setprio(1);
#pragma unroll
      for (int fm = 0; fm < 4; ++fm)
#pragma unroll
        for (int nf = 0; nf < 2; ++nf)
#pragma unroll
          for (int ks = 0; ks < 2; ++ks)
            acc[4 + fm][nf] = __builtin_amdgcn_mfma_f32_16x16x32_bf16(
                af[fm][ks], bf[nf][ks], acc[4 + fm][nf], 0, 0, 0);
      __builtin_amdgcn_s_setprio(0);
      __builtin_amdgcn_s_barrier();
    }
    cur = (cur == 2) ? 0 : cur + 1;
  }
#undef STAGE

  // ---- epilogue ----
  const float* bias_e = bias + (size_t)e * NT;
#pragma unroll
  for (int fm = 0; fm < 8; ++fm) {
#pragma unroll
    for (int r = 0; r < 4; ++r) {
      const int row = wm * 128 + ((fm & 4) << 4) + (fm & 3) * 16 + (lane >> 4) * 4 + r;
      if (m0 + row >= cnt) continue;
      const int p = rowp[row];
#pragma unroll
      for (int nf = 0; nf < 2; ++nf) {
        const int n = n0 + wn * 32 + nf * 16 + (lane & 15);
        const float v = acc[fm][nf][r] + bias_e[n];
        if (PHASE == 1) {
          const float g = 0.5f * v * (1.0f + erff(v * 0.70710678118654752f));
          hout[(size_t)p * NT + n] = f2bf(g);
        } else if (PHASE == 2) {
          yout[(size_t)p * NT + n] = gate_p[p] * v;
        } else {
          atomicAdd(&yout[(size_t)(p >> 1) * NT + n], gate_p[p] * v);
        }
      }
    }
  }
}

// ---------------- combine the two pair rows per token ------------------------
__global__ void combine_kernel(const float* __restrict__ yp, float* __restrict__ out) {
  const int i = blockIdx.x * blockDim.x + threadIdx.x;  // over T*D/4
  const int t = i >> 8;        // D/4 = 256 float4 per row
  const int d4 = i & 255;
  const float4 a = reinterpret_cast<const float4*>(yp)[(size_t)(2 * t) * 256 + d4];
  const float4 b = reinterpret_cast<const float4*>(yp)[(size_t)(2 * t) * 256 + 256 + d4];
  float4 o; o.x = a.x + b.x; o.y = a.y + b.y; o.z = a.z + b.z; o.w = a.w + b.w;
  reinterpret_cast<float4*>(out)[i] = o;
}

extern "C" void kernel_launch(void* const* d_in, const int* in_sizes, int n_in,
                              void* d_out, int out_size, void* d_ws, size_t ws_size,
                              hipStream_t stream) {
  const float* x  = (const float*)d_in[0];
  const float* Wr = (const float*)d_in[1];
  const float* br = (const float*)d_in[2];
  const float* gb = (const float*)d_in[3];
  const float* W1 = (const float*)d_in[4];
  const float* b1 = (const float*)d_in[5];
  const float* W2 = (const float*)d_in[6];
  const float* b2 = (const float*)d_in[7];
  float* out = (float*)d_out;

  char* ws = (char*)d_ws;
  size_t off = 0;
  int*   counts = (int*)(ws + off);   off += 256;
  int*   lists  = (int*)(ws + off);   off += (size_t)NE * T_TOK * 4;      // 128 KB
  float* gate_p = (float*)(ws + off); off += (size_t)T_TOK * 2 * 4;       // 32 KB
  u16*   xb     = (u16*)(ws + off);   off += (size_t)T_TOK * DIM * 2;     // 8 MB
  u16*   wbuf   = (u16*)(ws + off);   off += (size_t)NE * DIM * HID * 2;  // 64 MB
  u16*   hbuf   = (u16*)(ws + off);   off += (size_t)T_TOK * 2 * HID * 2; // 64 MB
  float* ypair  = (float*)(ws + off);
  const size_t need_full = off + (size_t)T_TOK * 2 * DIM * 4;             // +32 MB
  const bool use_ypair = (ws_size >= need_full);

  hipMemsetAsync(counts, 0, 32, stream);
  router_kernel<<<T_TOK / 4, 256, 0, stream>>>(x, Wr, br, gb, counts, lists, gate_p);
  cvt_x_kernel<<<(T_TOK * DIM / 8 + 255) / 256, 256, 0, stream>>>(x, xb, T_TOK * DIM / 8);
  cvt_w_kernel<<<dim3(HID / 64, DIM / 64, NE), 256, 0, stream>>>(W1, wbuf, DIM, HID);
  gemm_kernel<DIM, HID, 1><<<dim3(HID / 128, T_TOK * 2 / 256, NE), 512, 0, stream>>>(
      xb, wbuf, b1, counts, lists, gate_p, hbuf, nullptr);
  cvt_w_kernel<<<dim3(DIM / 64, HID / 64, NE), 256, 0, stream>>>(W2, wbuf, HID, DIM);
  if (use_ypair) {
    gemm_kernel<HID, DIM, 2><<<dim3(DIM / 128, T_TOK * 2 / 256, NE), 512, 0, stream>>>(
        hbuf, wbuf, b2, counts, lists, gate_p, nullptr, ypair);
    combine_kernel<<<T_TOK, 256, 0, stream>>>(ypair, out);
  } else {
    hipMemsetAsync(out, 0, (size_t)out_size * 4, stream);
    gemm_kernel<HID, DIM, 3><<<dim3(DIM / 128, T_TOK * 2 / 256, NE), 512, 0, stream>>>(
        hbuf, wbuf, b2, counts, lists, gate_p, nullptr, out);
  }
}

// Round 4
// 500.184 us; speedup vs baseline: 1.1270x; 1.1270x over previous
//
#include <hip/hip_runtime.h>
#include <hip/hip_bf16.h>
#include <stdint.h>
#include <stddef.h>

// MoE: T=4096 tokens, D=1024, H=4096, E=8, top-2. fp32 in/out, bf16 MFMA inside.
// Grouped GEMM: 256x256 tile, BK=64, 8 waves (wave 128x64, global-half-aligned
// quadrants), all-reg staging w/ 2-phase prefetch gap, dataflow-managed vmcnt,
// XOR-swizzled LDS, tile-table grid (x=m-tiles, y=n-panel), GEMM2 K-split x2.

#define T_TOK 4096
#define DIM   1024
#define HID   4096
#define NE    8
#define MT_MAX 40

typedef unsigned short u16;
typedef __bf16 bf16x8 __attribute__((ext_vector_type(8)));
typedef float  f32x4  __attribute__((ext_vector_type(4)));
typedef u16    u16x8  __attribute__((ext_vector_type(8)));

__device__ __forceinline__ u16 f2bf(float f) {
  union { float f; uint32_t u; } v; v.f = f;
  uint32_t u = v.u;
  return (u16)((u + 0x7fffu + ((u >> 16) & 1u)) >> 16);   // RNE
}

// ---------------- Router ----------------------------------------------------
__global__ void router_kernel(const float* __restrict__ x, const float* __restrict__ Wr,
                              const float* __restrict__ br, const float* __restrict__ gb,
                              int* __restrict__ counts, int* __restrict__ lists,
                              float* __restrict__ gate_p) {
  const int t = blockIdx.x * 4 + (threadIdx.x >> 6);
  const int lane = threadIdx.x & 63;
  const float* xr = x + (size_t)t * DIM;
  float acc[NE];
#pragma unroll
  for (int e = 0; e < NE; ++e) acc[e] = 0.f;
#pragma unroll
  for (int i = 0; i < DIM / 64; ++i) {
    const int k = i * 64 + lane;
    const float xv = xr[k];
    const float4 w0 = *reinterpret_cast<const float4*>(Wr + (size_t)k * NE);
    const float4 w1 = *reinterpret_cast<const float4*>(Wr + (size_t)k * NE + 4);
    acc[0] += xv * w0.x; acc[1] += xv * w0.y; acc[2] += xv * w0.z; acc[3] += xv * w0.w;
    acc[4] += xv * w1.x; acc[5] += xv * w1.y; acc[6] += xv * w1.z; acc[7] += xv * w1.w;
  }
#pragma unroll
  for (int off = 32; off >= 1; off >>= 1) {
#pragma unroll
    for (int e = 0; e < NE; ++e) acc[e] += __shfl_xor(acc[e], off);
  }
  if (lane == 0) {
    float lg[NE];
#pragma unroll
    for (int e = 0; e < NE; ++e) lg[e] = acc[e] + br[e] + gb[e];
    int i0 = 0;
#pragma unroll
    for (int e = 1; e < NE; ++e) if (lg[e] > lg[i0]) i0 = e;
    int i1 = (i0 == 0) ? 1 : 0;
#pragma unroll
    for (int e = 0; e < NE; ++e) if (e != i0 && lg[e] > lg[i1]) i1 = e;
    const float ev = expf(lg[i1] - lg[i0]);
    const float p0 = 1.f / (1.f + ev);
    const float p1 = ev / (1.f + ev);
    const int pos0 = atomicAdd(&counts[i0], 1);
    lists[i0 * T_TOK + pos0] = t * 2 + 0;
    const int pos1 = atomicAdd(&counts[i1], 1);
    lists[i1 * T_TOK + pos1] = t * 2 + 1;
    gate_p[t * 2 + 0] = p0;
    gate_p[t * 2 + 1] = p1;
  }
}

// ---------------- tile table: (expert, m0) per 256-row tile ------------------
__global__ void tile_table_kernel(const int* __restrict__ counts, int* __restrict__ tab) {
  if (threadIdx.x == 0) {
    int tot = 0;
    for (int e = 0; e < NE; ++e) {
      const int c = counts[e];
      const int nt = (c + 255) >> 8;
      for (int i = 0; i < nt && tot < MT_MAX; ++i) {
        tab[tot * 2] = e; tab[tot * 2 + 1] = i * 256; ++tot;
      }
    }
    for (; tot < MT_MAX; ++tot) tab[tot * 2] = -1;
  }
}

// ---------------- fp32 -> bf16 (x) ------------------------------------------
__global__ void cvt_x_kernel(const float* __restrict__ in, u16* __restrict__ out, int n8) {
  const int i = blockIdx.x * blockDim.x + threadIdx.x;
  if (i >= n8) return;
  const float4 a = reinterpret_cast<const float4*>(in)[2 * i];
  const float4 b = reinterpret_cast<const float4*>(in)[2 * i + 1];
  u16x8 r;
  r[0] = f2bf(a.x); r[1] = f2bf(a.y); r[2] = f2bf(a.z); r[3] = f2bf(a.w);
  r[4] = f2bf(b.x); r[5] = f2bf(b.y); r[6] = f2bf(b.z); r[7] = f2bf(b.w);
  *reinterpret_cast<u16x8*>(out + (size_t)i * 8) = r;
}

// ---------------- fp32 [E][K][N] -> bf16 [E][N][K] --------------------------
__global__ void cvt_w_kernel(const float* __restrict__ in, u16* __restrict__ out,
                             int K, int N) {
  __shared__ float tile[64][65];
  const int e = blockIdx.z;
  const int n0 = blockIdx.x * 64, k0 = blockIdx.y * 64;
  const int tid = threadIdx.x;
  const float* src = in + (size_t)e * K * N;
#pragma unroll
  for (int r = 0; r < 16; ++r) {
    const int kr = r * 4 + (tid >> 6);
    tile[kr][tid & 63] = src[(size_t)(k0 + kr) * N + n0 + (tid & 63)];
  }
  __syncthreads();
  u16* dst = out + (size_t)e * N * K;
#pragma unroll
  for (int r = 0; r < 8; ++r) {
    const int nr = r * 8 + (tid >> 5);
    const int kc = (tid & 31) * 2;
    ushort2 v;
    v.x = f2bf(tile[kc][nr]);
    v.y = f2bf(tile[kc + 1][nr]);
    *reinterpret_cast<ushort2*>(&dst[(size_t)(n0 + nr) * K + k0 + kc]) = v;
  }
}

// ---------------- GEMM helpers ----------------------------------------------
__device__ __forceinline__ void ld_afrags(const u16* sm, int cA, int fmh, int wm,
                                          int l15, int swz0, int swz1, bf16x8 af[4][2]) {
#pragma unroll
  for (int f = 0; f < 4; ++f) {
    const int r = fmh * 128 + wm * 64 + f * 16 + l15;
    af[f][0] = *reinterpret_cast<const bf16x8*>(&sm[cA + r * 64 + swz0 * 8]);
    af[f][1] = *reinterpret_cast<const bf16x8*>(&sm[cA + r * 64 + swz1 * 8]);
  }
}
__device__ __forceinline__ void ld_bfrags(const u16* sm, int cA, int nfh, int wn,
                                          int l15, int swz0, int swz1, bf16x8 bfr[2][2]) {
#pragma unroll
  for (int g = 0; g < 2; ++g) {
    const int r = nfh * 128 + wn * 32 + g * 16 + l15;
    bfr[g][0] = *reinterpret_cast<const bf16x8*>(&sm[32768 + cA + r * 64 + swz0 * 8]);
    bfr[g][1] = *reinterpret_cast<const bf16x8*>(&sm[32768 + cA + r * 64 + swz1 * 8]);
  }
}
__device__ __forceinline__ void wr_half(u16* sm, int baseoff, int h, int trow, int wslot,
                                        const bf16x8 v[2]) {
#pragma unroll
  for (int j = 0; j < 2; ++j) {
    const int r = h * 128 + j * 64 + trow;
    *reinterpret_cast<bf16x8*>(&sm[baseoff + r * 64 + wslot * 8]) = v[j];
  }
}

#define PH_SYNC()                                           \
  asm volatile("s_waitcnt lgkmcnt(0)" ::: "memory");        \
  __builtin_amdgcn_s_barrier();                             \
  __builtin_amdgcn_sched_barrier(0);

#define MMQ(FMH, NFH, AF, BF)                                                   \
  __builtin_amdgcn_s_setprio(1);                                                \
  _Pragma("unroll") for (int f_ = 0; f_ < 4; ++f_)                              \
  _Pragma("unroll") for (int g_ = 0; g_ < 2; ++g_)                              \
  _Pragma("unroll") for (int ks_ = 0; ks_ < 2; ++ks_)                           \
    acc[(FMH) * 4 + f_][(NFH) * 2 + g_] =                                       \
        __builtin_amdgcn_mfma_f32_16x16x32_bf16(                                \
            AF[f_][ks_], BF[g_][ks_], acc[(FMH) * 4 + f_][(NFH) * 2 + g_],      \
            0, 0, 0);                                                           \
  __builtin_amdgcn_s_setprio(0);

// ---------------- Grouped GEMM ----------------------------------------------
// PHASE 1: h = gelu(x*W1+b1) -> bf16 ; PHASE 2: ypair_z = g*(h*W2 + [z==0]b2)
// PHASE 3: atomicAdd into out (fallback)
template <int KT, int NT, int NSPLIT, int PHASE>
__global__ __launch_bounds__(512, 2)
void gemm_kernel(const u16* __restrict__ Abase, const u16* __restrict__ Bt,
                 const float* __restrict__ bias, const int* __restrict__ counts,
                 const int* __restrict__ lists, const float* __restrict__ gate_p,
                 const int* __restrict__ tab,
                 u16* __restrict__ hout, float* __restrict__ yout) {
  const int e = tab[blockIdx.x * 2];
  if (e < 0) return;
  const int m0 = tab[blockIdx.x * 2 + 1];
  const int cnt = counts[e];
  const int n0 = blockIdx.y * 256;
  const int z = blockIdx.z;
  const int kbase = z * (KT / NSPLIT);
  constexpr int nkt = (KT / NSPLIT) / 64;

  const int tid = threadIdx.x;
  const int lane = tid & 63, w = tid >> 6;
  const int wm = w >> 2, wn = w & 3;
  const int l15 = lane & 15, lks = lane >> 4;
  const int rb = l15 & 7;
  const int swz0 = lks ^ rb, swz1 = (4 + lks) ^ rb;

  __shared__ alignas(16) u16 lds[65536];   // A: [c][256][64] @ c*16384 ; B: +32768
  __shared__ int rowp[256];

  if (tid < 256) {
    const int idx = m0 + tid;
    rowp[tid] = lists[e * T_TOK + (idx < cnt ? idx : cnt - 1)];
  }
  __syncthreads();

  const int trow = tid >> 3;           // 0..63
  const int tslot = tid & 7;
  const int wslot = tslot ^ (trow & 7);
  const u16* aP[2][2];
  const u16* bP[2][2];
#pragma unroll
  for (int h = 0; h < 2; ++h)
#pragma unroll
    for (int j = 0; j < 2; ++j) {
      const int r = h * 128 + j * 64 + trow;
      const int p = rowp[r];
      const int arow = (PHASE == 1) ? (p >> 1) : p;
      aP[h][j] = Abase + (size_t)arow * KT + kbase + tslot * 8;
      bP[h][j] = Bt + ((size_t)e * NT + n0 + r) * KT + kbase + tslot * 8;
    }

  f32x4 acc[8][4];
#pragma unroll
  for (int a = 0; a < 8; ++a)
#pragma unroll
    for (int b = 0; b < 4; ++b) acc[a][b] = f32x4{0.f, 0.f, 0.f, 0.f};

  bf16x8 aL0[2], aL1[2], bL0[2], bL1[2], af[4][2], bfr[2][2];

  // ---- prologue: write A0[0],B0[0]; hold A1[0],B1[0] in regs ----
  {
    bf16x8 w0[2], w1[2];
#pragma unroll
    for (int j = 0; j < 2; ++j) {
      w0[j]  = *reinterpret_cast<const bf16x8*>(aP[0][j]);
      w1[j]  = *reinterpret_cast<const bf16x8*>(bP[0][j]);
      aL1[j] = *reinterpret_cast<const bf16x8*>(aP[1][j]);
      bL1[j] = *reinterpret_cast<const bf16x8*>(bP[1][j]);
    }
    wr_half(lds, 0, 0, trow, wslot, w0);
    wr_half(lds, 32768, 0, trow, wslot, w1);
  }

#define TILE(C, T)                                                                   \
  {                                                                                  \
    constexpr int cA = (C) * 16384;                                                  \
    constexpr int nA = ((C) ^ 1) * 16384;                                            \
    const int tn = (T) + 1;                                                          \
    /* q0: reads A0,B0 ; write B1[c] ; load A0' */                                   \
    PH_SYNC();                                                                       \
    ld_afrags(lds, cA, 0, wm, l15, swz0, swz1, af);                                  \
    ld_bfrags(lds, cA, 0, wn, l15, swz0, swz1, bfr);                                 \
    if (tn < nkt) {                                                                  \
      aL0[0] = *reinterpret_cast<const bf16x8*>(aP[0][0] + tn * 64);                 \
      aL0[1] = *reinterpret_cast<const bf16x8*>(aP[0][1] + tn * 64);                 \
    }                                                                                \
    wr_half(lds, 32768 + cA, 1, trow, wslot, bL1);                                   \
    MMQ(0, 0, af, bfr);                                                              \
    /* q1: reads B1 ; write A1[c] ; load B0' */                                      \
    PH_SYNC();                                                                       \
    ld_bfrags(lds, cA, 1, wn, l15, swz0, swz1, bfr);                                 \
    if (tn < nkt) {                                                                  \
      bL0[0] = *reinterpret_cast<const bf16x8*>(bP[0][0] + tn * 64);                 \
      bL0[1] = *reinterpret_cast<const bf16x8*>(bP[0][1] + tn * 64);                 \
    }                                                                                \
    wr_half(lds, cA, 1, trow, wslot, aL1);                                           \
    MMQ(0, 1, af, bfr);                                                              \
    /* q2: reads A1,B0 ; write A0'->n ; load B1' */                                  \
    PH_SYNC();                                                                       \
    ld_afrags(lds, cA, 1, wm, l15, swz0, swz1, af);                                  \
    ld_bfrags(lds, cA, 0, wn, l15, swz0, swz1, bfr);                                 \
    if (tn < nkt) {                                                                  \
      bL1[0] = *reinterpret_cast<const bf16x8*>(bP[1][0] + tn * 64);                 \
      bL1[1] = *reinterpret_cast<const bf16x8*>(bP[1][1] + tn * 64);                 \
    }                                                                                \
    wr_half(lds, nA, 0, trow, wslot, aL0);                                           \
    MMQ(1, 0, af, bfr);                                                              \
    /* q3: reads B1 ; write B0'->n ; load A1' (no barrier) */                        \
    ld_bfrags(lds, cA, 1, wn, l15, swz0, swz1, bfr);                                 \
    if (tn < nkt) {                                                                  \
      aL1[0] = *reinterpret_cast<const bf16x8*>(aP[1][0] + tn * 64);                 \
      aL1[1] = *reinterpret_cast<const bf16x8*>(aP[1][1] + tn * 64);                 \
    }                                                                                \
    wr_half(lds, 32768 + nA, 0, trow, wslot, bL0);                                   \
    MMQ(1, 1, af, bfr);                                                              \
  }

  for (int t = 0; t < nkt; t += 2) {
    TILE(0, t);
    TILE(1, t + 1);
  }
#undef TILE

  // ---- epilogue ----
  const float* bias_e = bias + (size_t)e * NT;
  const float bz = (z == 0) ? 1.f : 0.f;
#pragma unroll
  for (int fm = 0; fm < 8; ++fm) {
    const int rbase = (fm >> 2) * 128 + wm * 64 + (fm & 3) * 16 + (lane >> 4) * 4;
#pragma unroll
    for (int r = 0; r < 4; ++r) {
      const int row = rbase + r;
      if (m0 + row >= cnt) continue;
      const int p = rowp[row];
#pragma unroll
      for (int nf = 0; nf < 4; ++nf) {
        const int n = n0 + (nf >> 1) * 128 + wn * 32 + (nf & 1) * 16 + l15;
        const float v = acc[fm][nf][r];
        if (PHASE == 1) {
          const float vb = v + bias_e[n];
          const float g = 0.5f * vb * (1.0f + erff(vb * 0.70710678118654752f));
          hout[(size_t)p * NT + n] = f2bf(g);
        } else if (PHASE == 2) {
          yout[(size_t)z * T_TOK * 2 * NT + (size_t)p * NT + n] =
              gate_p[p] * (v + bz * bias_e[n]);
        } else {
          atomicAdd(&yout[(size_t)(p >> 1) * NT + n], gate_p[p] * (v + bz * bias_e[n]));
        }
      }
    }
  }
}

// ---------------- combine: sum 2 pair rows x 2 k-split buffers ----------------
__global__ void combine4_kernel(const float* __restrict__ yp, float* __restrict__ out) {
  const int i = blockIdx.x * blockDim.x + threadIdx.x;  // over T*D/4
  const int t = i >> 8, d4 = i & 255;
  const size_t r0 = (size_t)(2 * t) * 256 + d4;
  const size_t zoff = (size_t)T_TOK * 2 * DIM / 4;
  const float4 a = reinterpret_cast<const float4*>(yp)[r0];
  const float4 b = reinterpret_cast<const float4*>(yp)[r0 + 256];
  const float4 c = reinterpret_cast<const float4*>(yp)[zoff + r0];
  const float4 d = reinterpret_cast<const float4*>(yp)[zoff + r0 + 256];
  float4 o;
  o.x = a.x + b.x + c.x + d.x; o.y = a.y + b.y + c.y + d.y;
  o.z = a.z + b.z + c.z + d.z; o.w = a.w + b.w + c.w + d.w;
  reinterpret_cast<float4*>(out)[i] = o;
}

extern "C" void kernel_launch(void* const* d_in, const int* in_sizes, int n_in,
                              void* d_out, int out_size, void* d_ws, size_t ws_size,
                              hipStream_t stream) {
  const float* x  = (const float*)d_in[0];
  const float* Wr = (const float*)d_in[1];
  const float* br = (const float*)d_in[2];
  const float* gb = (const float*)d_in[3];
  const float* W1 = (const float*)d_in[4];
  const float* b1 = (const float*)d_in[5];
  const float* W2 = (const float*)d_in[6];
  const float* b2 = (const float*)d_in[7];
  float* out = (float*)d_out;

  char* ws = (char*)d_ws;
  size_t off = 0;
  int*   counts = (int*)(ws + off);   off += 256;
  int*   ttab   = (int*)(ws + off);   off += 512;
  int*   lists  = (int*)(ws + off);   off += (size_t)NE * T_TOK * 4;      // 128 KB
  float* gate_p = (float*)(ws + off); off += (size_t)T_TOK * 2 * 4;       // 32 KB
  u16*   xb     = (u16*)(ws + off);   off += (size_t)T_TOK * DIM * 2;     // 8 MB
  u16*   wbuf   = (u16*)(ws + off);   off += (size_t)NE * DIM * HID * 2;  // 64 MB
  u16*   hbuf   = (u16*)(ws + off);   off += (size_t)T_TOK * 2 * HID * 2; // 64 MB
  float* ypair  = (float*)(ws + off);
  const size_t need_full = off + (size_t)2 * T_TOK * 2 * DIM * 4;         // +64 MB
  const bool use_ypair = (ws_size >= need_full);

  hipMemsetAsync(counts, 0, 32, stream);
  router_kernel<<<T_TOK / 4, 256, 0, stream>>>(x, Wr, br, gb, counts, lists, gate_p);
  tile_table_kernel<<<1, 64, 0, stream>>>(counts, ttab);
  cvt_x_kernel<<<(T_TOK * DIM / 8 + 255) / 256, 256, 0, stream>>>(x, xb, T_TOK * DIM / 8);
  cvt_w_kernel<<<dim3(HID / 64, DIM / 64, NE), 256, 0, stream>>>(W1, wbuf, DIM, HID);
  gemm_kernel<DIM, HID, 1, 1><<<dim3(MT_MAX, HID / 256, 1), 512, 0, stream>>>(
      xb, wbuf, b1, counts, lists, gate_p, ttab, hbuf, nullptr);
  cvt_w_kernel<<<dim3(DIM / 64, HID / 64, NE), 256, 0, stream>>>(W2, wbuf, HID, DIM);
  if (use_ypair) {
    gemm_kernel<HID, DIM, 2, 2><<<dim3(MT_MAX, DIM / 256, 2), 512, 0, stream>>>(
        hbuf, wbuf, b2, counts, lists, gate_p, ttab, nullptr, ypair);
    combine4_kernel<<<T_TOK * DIM / 4 / 256, 256, 0, stream>>>(ypair, out);
  } else {
    hipMemsetAsync(out, 0, (size_t)out_size * 4, stream);
    gemm_kernel<HID, DIM, 2, 3><<<dim3(MT_MAX, DIM / 256, 2), 512, 0, stream>>>(
        hbuf, wbuf, b2, counts, lists, gate_p, ttab, nullptr, out);
  }
}

// Round 5
// 497.918 us; speedup vs baseline: 1.1321x; 1.0046x over previous
//
#include <hip/hip_runtime.h>
#include <hip/hip_bf16.h>
#include <stdint.h>
#include <stddef.h>

// MoE: T=4096 tokens, D=1024, H=4096, E=8, top-2. fp32 in/out, bf16 MFMA inside.
// Grouped GEMM: 256x256 tile, BK=64, 8 waves (wave 128x64), m201-style 8-phase
// schedule: global_load_lds quarter-tile staging (2/phase), counted vmcnt(6) at
// phases 4/8 only, lgkmcnt(0)+setprio around each 16-MFMA quadrant, XOR swizzle.

#define T_TOK 4096
#define DIM   1024
#define HID   4096
#define NE    8
#define MT_MAX 40

typedef unsigned short u16;
typedef __bf16 bf16x8 __attribute__((ext_vector_type(8)));
typedef float  f32x4  __attribute__((ext_vector_type(4)));
typedef u16    u16x8  __attribute__((ext_vector_type(8)));

__device__ __forceinline__ u16 f2bf(float f) {
  union { float f; uint32_t u; } v; v.f = f;
  uint32_t u = v.u;
  return (u16)((u + 0x7fffu + ((u >> 16) & 1u)) >> 16);   // RNE
}

__device__ __forceinline__ void async_load16(const void* g, void* l) {
  typedef __attribute__((address_space(1))) void GPtr;
  typedef __attribute__((address_space(3))) void LPtr;
  __builtin_amdgcn_global_load_lds((GPtr*)g, (LPtr*)l, 16, 0, 0);
}

// ---------------- Router ----------------------------------------------------
__global__ void router_kernel(const float* __restrict__ x, const float* __restrict__ Wr,
                              const float* __restrict__ br, const float* __restrict__ gb,
                              int* __restrict__ counts, int* __restrict__ lists,
                              float* __restrict__ gate_p) {
  const int t = blockIdx.x * 4 + (threadIdx.x >> 6);
  const int lane = threadIdx.x & 63;
  const float* xr = x + (size_t)t * DIM;
  float acc[NE];
#pragma unroll
  for (int e = 0; e < NE; ++e) acc[e] = 0.f;
#pragma unroll
  for (int i = 0; i < DIM / 64; ++i) {
    const int k = i * 64 + lane;
    const float xv = xr[k];
    const float4 w0 = *reinterpret_cast<const float4*>(Wr + (size_t)k * NE);
    const float4 w1 = *reinterpret_cast<const float4*>(Wr + (size_t)k * NE + 4);
    acc[0] += xv * w0.x; acc[1] += xv * w0.y; acc[2] += xv * w0.z; acc[3] += xv * w0.w;
    acc[4] += xv * w1.x; acc[5] += xv * w1.y; acc[6] += xv * w1.z; acc[7] += xv * w1.w;
  }
#pragma unroll
  for (int off = 32; off >= 1; off >>= 1) {
#pragma unroll
    for (int e = 0; e < NE; ++e) acc[e] += __shfl_xor(acc[e], off);
  }
  if (lane == 0) {
    float lg[NE];
#pragma unroll
    for (int e = 0; e < NE; ++e) lg[e] = acc[e] + br[e] + gb[e];
    int i0 = 0;
#pragma unroll
    for (int e = 1; e < NE; ++e) if (lg[e] > lg[i0]) i0 = e;
    int i1 = (i0 == 0) ? 1 : 0;
#pragma unroll
    for (int e = 0; e < NE; ++e) if (e != i0 && lg[e] > lg[i1]) i1 = e;
    const float ev = expf(lg[i1] - lg[i0]);
    const float p0 = 1.f / (1.f + ev);
    const float p1 = ev / (1.f + ev);
    const int pos0 = atomicAdd(&counts[i0], 1);
    lists[i0 * T_TOK + pos0] = t * 2 + 0;
    const int pos1 = atomicAdd(&counts[i1], 1);
    lists[i1 * T_TOK + pos1] = t * 2 + 1;
    gate_p[t * 2 + 0] = p0;
    gate_p[t * 2 + 1] = p1;
  }
}

// ---------------- tile table: (expert, m0) per 256-row tile ------------------
__global__ void tile_table_kernel(const int* __restrict__ counts, int* __restrict__ tab) {
  if (threadIdx.x == 0) {
    int tot = 0;
    for (int e = 0; e < NE; ++e) {
      const int c = counts[e];
      const int nt = (c + 255) >> 8;
      for (int i = 0; i < nt && tot < MT_MAX; ++i) {
        tab[tot * 2] = e; tab[tot * 2 + 1] = i * 256; ++tot;
      }
    }
    for (; tot < MT_MAX; ++tot) tab[tot * 2] = -1;
  }
}

// ---------------- fp32 -> bf16 (x) ------------------------------------------
__global__ void cvt_x_kernel(const float* __restrict__ in, u16* __restrict__ out, int n8) {
  const int i = blockIdx.x * blockDim.x + threadIdx.x;
  if (i >= n8) return;
  const float4 a = reinterpret_cast<const float4*>(in)[2 * i];
  const float4 b = reinterpret_cast<const float4*>(in)[2 * i + 1];
  u16x8 r;
  r[0] = f2bf(a.x); r[1] = f2bf(a.y); r[2] = f2bf(a.z); r[3] = f2bf(a.w);
  r[4] = f2bf(b.x); r[5] = f2bf(b.y); r[6] = f2bf(b.z); r[7] = f2bf(b.w);
  *reinterpret_cast<u16x8*>(out + (size_t)i * 8) = r;
}

// ---------------- fp32 [E][K][N] -> bf16 [E][N][K] --------------------------
__global__ void cvt_w_kernel(const float* __restrict__ in, u16* __restrict__ out,
                             int K, int N) {
  __shared__ float tile[64][65];
  const int e = blockIdx.z;
  const int n0 = blockIdx.x * 64, k0 = blockIdx.y * 64;
  const int tid = threadIdx.x;
  const float* src = in + (size_t)e * K * N;
#pragma unroll
  for (int r = 0; r < 16; ++r) {
    const int kr = r * 4 + (tid >> 6);
    tile[kr][tid & 63] = src[(size_t)(k0 + kr) * N + n0 + (tid & 63)];
  }
  __syncthreads();
  u16* dst = out + (size_t)e * N * K;
#pragma unroll
  for (int r = 0; r < 8; ++r) {
    const int nr = r * 8 + (tid >> 5);
    const int kc = (tid & 31) * 2;
    ushort2 v;
    v.x = f2bf(tile[kc][nr]);
    v.y = f2bf(tile[kc + 1][nr]);
    *reinterpret_cast<ushort2*>(&dst[(size_t)(n0 + nr) * K + k0 + kc]) = v;
  }
}

// ---------------- Grouped GEMM: 8-phase counted-vmcnt pipeline ---------------
// LDS quarters (8 KB = 4096 u16 each, 64 rows x 64 k):
//   A.q(c,h,s) @ ((c*2+h)*2+s)*4096        rows h*128+s*64+0..63
//   B.q(c,h,s) @ 32768 + ((c*2+h)*2+s)*4096  n-rows h*128+s*64+0..63
// Stage: 1 gload_lds/thread/quarter; dest = qbase + w*512 (linear, lane*16B HW)
// Source k-slot pre-swizzled: (tid&7) ^ ((tid>>3)&7); read slot ls ^ (row&7).
template <int KT, int NT, int NSPLIT, int PHASE>
__global__ __launch_bounds__(512, 2)
void gemm_kernel(const u16* __restrict__ Abase, const u16* __restrict__ Bt,
                 const float* __restrict__ bias, const int* __restrict__ counts,
                 const int* __restrict__ lists, const float* __restrict__ gate_p,
                 const int* __restrict__ tab,
                 u16* __restrict__ hout, float* __restrict__ yout) {
  const int e = tab[blockIdx.x * 2];
  if (e < 0) return;
  const int m0 = tab[blockIdx.x * 2 + 1];
  const int cnt = counts[e];
  const int n0 = blockIdx.y * 256;
  const int z = blockIdx.z;
  const int kbase = z * (KT / NSPLIT);
  constexpr int nkt = (KT / NSPLIT) / 64;
  constexpr int niter = nkt / 2;

  const int tid = threadIdx.x;
  const int lane = tid & 63, w = tid >> 6;
  const int wm = w >> 2, wn = w & 3;          // wave: rows wm*128+0..127, cols wn*64+0..63
  const int bh = wn >> 1, bs = wn & 1;        // wave's B quarter
  const int l15 = lane & 15, lks = lane >> 4;

  __shared__ alignas(16) u16 lds[65536];      // 128 KB
  __shared__ int rowp[256];

  if (tid < 256) {
    const int idx = m0 + tid;
    rowp[tid] = lists[e * T_TOK + (idx < cnt ? idx : cnt - 1)];
  }
  __syncthreads();

  // staging source pointers (per thread): row tid>>3 of each quarter, swizzled slot
  const int sslot = (tid & 7) ^ ((tid >> 3) & 7);
  const u16* aPtr[2][2];
  const u16* bPtr[2][2];
#pragma unroll
  for (int h = 0; h < 2; ++h)
#pragma unroll
    for (int s = 0; s < 2; ++s) {
      const int r = h * 128 + s * 64 + (tid >> 3);
      const int p = rowp[r];
      const int arow = (PHASE == 1) ? (p >> 1) : p;
      aPtr[h][s] = Abase + (size_t)arow * KT + kbase + sslot * 8;
      bPtr[h][s] = Bt + ((size_t)e * NT + n0 + r) * KT + kbase + sslot * 8;
    }

  // ds_read offsets (u16 units) within a quarter, per k-step
  int aoff[2];
#pragma unroll
  for (int k = 0; k < 2; ++k)
    aoff[k] = l15 * 64 + (((k * 4 + lks) ^ (l15 & 7)) * 8);

  f32x4 acc[8][4];
#pragma unroll
  for (int a = 0; a < 8; ++a)
#pragma unroll
    for (int b = 0; b < 4; ++b) acc[a][b] = f32x4{0.f, 0.f, 0.f, 0.f};

  bf16x8 af[4][2], bfr[4][2];

#define RDA(C, FMH)                                                            \
  _Pragma("unroll") for (int f_ = 0; f_ < 4; ++f_)                             \
  _Pragma("unroll") for (int k_ = 0; k_ < 2; ++k_)                             \
    af[f_][k_] = *reinterpret_cast<const bf16x8*>(                             \
        &lds[(((C) * 2 + wm) * 2 + (FMH)) * 4096 + f_ * 1024 + aoff[k_]]);

#define RDB(C)                                                                 \
  _Pragma("unroll") for (int g_ = 0; g_ < 4; ++g_)                             \
  _Pragma("unroll") for (int k_ = 0; k_ < 2; ++k_)                             \
    bfr[g_][k_] = *reinterpret_cast<const bf16x8*>(                            \
        &lds[32768 + (((C) * 2 + bh) * 2 + bs) * 4096 + g_ * 1024 + aoff[k_]]);

#define SGA(C, S, TT)                                                          \
  _Pragma("unroll") for (int h_ = 0; h_ < 2; ++h_)                             \
    async_load16(aPtr[h_][S] + (TT) * 64,                                      \
                 &lds[(((C) * 2 + h_) * 2 + (S)) * 4096 + w * 512]);

#define SGB(C, H, TT)                                                          \
  _Pragma("unroll") for (int s_ = 0; s_ < 2; ++s_)                             \
    async_load16(bPtr[H][s_] + (TT) * 64,                                      \
                 &lds[32768 + (((C) * 2 + (H)) * 2 + s_) * 4096 + w * 512]);

#define MMQ(FMH, FNH)                                                          \
  _Pragma("unroll") for (int f_ = 0; f_ < 4; ++f_)                             \
  _Pragma("unroll") for (int g_ = 0; g_ < 2; ++g_)                             \
  _Pragma("unroll") for (int k_ = 0; k_ < 2; ++k_)                             \
    acc[(FMH) * 4 + f_][(FNH) * 2 + g_] =                                      \
        __builtin_amdgcn_mfma_f32_16x16x32_bf16(                               \
            af[f_][k_], bfr[(FNH) * 2 + g_][k_],                               \
            acc[(FMH) * 4 + f_][(FNH) * 2 + g_], 0, 0, 0);

#define CORE(FMH, FNH)                                                         \
  __builtin_amdgcn_s_barrier();                                                \
  asm volatile("s_waitcnt lgkmcnt(0)" ::: "memory");                           \
  __builtin_amdgcn_sched_barrier(0);                                           \
  __builtin_amdgcn_s_setprio(1);                                               \
  MMQ(FMH, FNH);                                                               \
  __builtin_amdgcn_s_setprio(0);                                               \
  __builtin_amdgcn_sched_barrier(0);

#define BAR() __builtin_amdgcn_s_barrier();

#define ITER(T, LAST)                                                          \
  {                                                                            \
    RDA(0, 0); RDB(0);                                                         \
    SGA(1, 1, (T) + 1);                      /* A.s1[t+1] -> buf1 */           \
    CORE(0, 0) BAR()                                                           \
    if (!(LAST)) { SGA(0, 0, (T) + 2); }     /* A.s0[t+2] -> buf0 */           \
    CORE(0, 1) BAR()                                                           \
    RDA(0, 1);                                                                 \
    if (!(LAST)) { SGB(0, 0, (T) + 2); }     /* B.h0[t+2] */                   \
    CORE(1, 0) BAR()                                                           \
    if (!(LAST)) { SGB(0, 1, (T) + 2); }     /* B.h1[t+2] */                   \
    CORE(1, 1)                                                                 \
    if (LAST) { asm volatile("s_waitcnt vmcnt(0)" ::: "memory"); }             \
    else      { asm volatile("s_waitcnt vmcnt(6)" ::: "memory"); }             \
    __builtin_amdgcn_sched_barrier(0);                                         \
    BAR()                                                                      \
    RDA(1, 0); RDB(1);                                                         \
    if (!(LAST)) { SGA(0, 1, (T) + 2); }     /* A.s1[t+2] */                   \
    CORE(0, 0) BAR()                                                           \
    if (!(LAST)) { SGA(1, 0, (T) + 3); }     /* A.s0[t+3] -> buf1 */           \
    CORE(0, 1) BAR()                                                           \
    RDA(1, 1);                                                                 \
    if (!(LAST)) { SGB(1, 0, (T) + 3); }     /* B.h0[t+3] */                   \
    CORE(1, 0) BAR()                                                           \
    if (!(LAST)) { SGB(1, 1, (T) + 3); }     /* B.h1[t+3] */                   \
    CORE(1, 1)                                                                 \
    if (!(LAST)) {                                                             \
      asm volatile("s_waitcnt vmcnt(6)" ::: "memory");                         \
      __builtin_amdgcn_sched_barrier(0);                                       \
    }                                                                          \
    BAR()                                                                      \
  }

  // ---- prologue: tile0 (8 quarters) + tile1 {A.s0, B} (6 quarters) ----
  SGA(0, 0, 0); SGB(0, 0, 0); SGB(0, 1, 0); SGA(0, 1, 0);
  SGA(1, 0, 1); SGB(1, 0, 1); SGB(1, 1, 1);
  asm volatile("s_waitcnt vmcnt(6)" ::: "memory");   // tile0 landed
  __builtin_amdgcn_sched_barrier(0);
  __builtin_amdgcn_s_barrier();

  for (int it = 0; it < niter - 1; ++it) {
    const int t = 2 * it;
    ITER(t, false);
  }
  ITER(nkt - 2, true);

#undef ITER
#undef CORE
#undef MMQ
#undef SGB
#undef SGA
#undef RDB
#undef RDA
#undef BAR

  // ---- epilogue: row = wm*128 + fmh*64 + f2*16 + (lane>>4)*4 + r ----
  const float* bias_e = bias + (size_t)e * NT;
  const float bz = (z == 0) ? 1.f : 0.f;
#pragma unroll
  for (int fm = 0; fm < 8; ++fm) {
    const int rbase = wm * 128 + (fm >> 2) * 64 + (fm & 3) * 16 + (lane >> 4) * 4;
#pragma unroll
    for (int r = 0; r < 4; ++r) {
      const int row = rbase + r;
      if (m0 + row >= cnt) continue;
      const int p = rowp[row];
#pragma unroll
      for (int nf = 0; nf < 4; ++nf) {
        const int n = n0 + wn * 64 + nf * 16 + l15;
        const float v = acc[fm][nf][r];
        if (PHASE == 1) {
          const float vb = v + bias_e[n];
          const float g = 0.5f * vb * (1.0f + erff(vb * 0.70710678118654752f));
          hout[(size_t)p * NT + n] = f2bf(g);
        } else if (PHASE == 2) {
          yout[(size_t)z * T_TOK * 2 * NT + (size_t)p * NT + n] =
              gate_p[p] * (v + bz * bias_e[n]);
        } else {
          atomicAdd(&yout[(size_t)(p >> 1) * NT + n], gate_p[p] * (v + bz * bias_e[n]));
        }
      }
    }
  }
}

// ---------------- combine: sum 2 pair rows x 2 k-split buffers ----------------
__global__ void combine4_kernel(const float* __restrict__ yp, float* __restrict__ out) {
  const int i = blockIdx.x * blockDim.x + threadIdx.x;  // over T*D/4
  const int t = i >> 8, d4 = i & 255;
  const size_t r0 = (size_t)(2 * t) * 256 + d4;
  const size_t zoff = (size_t)T_TOK * 2 * DIM / 4;
  const float4 a = reinterpret_cast<const float4*>(yp)[r0];
  const float4 b = reinterpret_cast<const float4*>(yp)[r0 + 256];
  const float4 c = reinterpret_cast<const float4*>(yp)[zoff + r0];
  const float4 d = reinterpret_cast<const float4*>(yp)[zoff + r0 + 256];
  float4 o;
  o.x = a.x + b.x + c.x + d.x; o.y = a.y + b.y + c.y + d.y;
  o.z = a.z + b.z + c.z + d.z; o.w = a.w + b.w + c.w + d.w;
  reinterpret_cast<float4*>(out)[i] = o;
}

extern "C" void kernel_launch(void* const* d_in, const int* in_sizes, int n_in,
                              void* d_out, int out_size, void* d_ws, size_t ws_size,
                              hipStream_t stream) {
  const float* x  = (const float*)d_in[0];
  const float* Wr = (const float*)d_in[1];
  const float* br = (const float*)d_in[2];
  const float* gb = (const float*)d_in[3];
  const float* W1 = (const float*)d_in[4];
  const float* b1 = (const float*)d_in[5];
  const float* W2 = (const float*)d_in[6];
  const float* b2 = (const float*)d_in[7];
  float* out = (float*)d_out;

  char* ws = (char*)d_ws;
  size_t off = 0;
  int*   counts = (int*)(ws + off);   off += 256;
  int*   ttab   = (int*)(ws + off);   off += 512;
  int*   lists  = (int*)(ws + off);   off += (size_t)NE * T_TOK * 4;      // 128 KB
  float* gate_p = (float*)(ws + off); off += (size_t)T_TOK * 2 * 4;       // 32 KB
  u16*   xb     = (u16*)(ws + off);   off += (size_t)T_TOK * DIM * 2;     // 8 MB
  u16*   wbuf   = (u16*)(ws + off);   off += (size_t)NE * DIM * HID * 2;  // 64 MB
  u16*   hbuf   = (u16*)(ws + off);   off += (size_t)T_TOK * 2 * HID * 2; // 64 MB
  float* ypair  = (float*)(ws + off);
  const size_t need_full = off + (size_t)2 * T_TOK * 2 * DIM * 4;         // +64 MB
  const bool use_ypair = (ws_size >= need_full);

  hipMemsetAsync(counts, 0, 32, stream);
  router_kernel<<<T_TOK / 4, 256, 0, stream>>>(x, Wr, br, gb, counts, lists, gate_p);
  tile_table_kernel<<<1, 64, 0, stream>>>(counts, ttab);
  cvt_x_kernel<<<(T_TOK * DIM / 8 + 255) / 256, 256, 0, stream>>>(x, xb, T_TOK * DIM / 8);
  cvt_w_kernel<<<dim3(HID / 64, DIM / 64, NE), 256, 0, stream>>>(W1, wbuf, DIM, HID);
  gemm_kernel<DIM, HID, 1, 1><<<dim3(MT_MAX, HID / 256, 1), 512, 0, stream>>>(
      xb, wbuf, b1, counts, lists, gate_p, ttab, hbuf, nullptr);
  cvt_w_kernel<<<dim3(DIM / 64, HID / 64, NE), 256, 0, stream>>>(W2, wbuf, HID, DIM);
  if (use_ypair) {
    gemm_kernel<HID, DIM, 2, 2><<<dim3(MT_MAX, DIM / 256, 2), 512, 0, stream>>>(
        hbuf, wbuf, b2, counts, lists, gate_p, ttab, nullptr, ypair);
    combine4_kernel<<<T_TOK * DIM / 4 / 256, 256, 0, stream>>>(ypair, out);
  } else {
    hipMemsetAsync(out, 0, (size_t)out_size * 4, stream);
    gemm_kernel<HID, DIM, 2, 3><<<dim3(MT_MAX, DIM / 256, 2), 512, 0, stream>>>(
        hbuf, wbuf, b2, counts, lists, gate_p, ttab, nullptr, out);
  }
}